// Round 2
// baseline (524.247 us; speedup 1.0000x reference)
//
#include <hip/hip_runtime.h>
#include <math.h>

#define HH 256
#define WW 256
#define CTOT 256
#define HW (HH * WW)

// One lane = one output bin (49 of 64 lanes active).
// One wave = one channel-group (8 orientation channels) of one RoI.
// Block = 4 waves -> 4 channel-groups; grid = (n_rois, 8) -> 32 groups = 256 ch.
// All geometry (4 samples x 4 corners: offsets + weights) lives in registers;
// no LDS, no __syncthreads.
__global__ __launch_bounds__(256) void riroi_rotated_kernel(
    const float* __restrict__ feats,   // (B, 256, 256, 256)
    const float* __restrict__ rois,    // (n_rois, 6)
    float* __restrict__ out)           // (n_rois, 256, 7, 7)
{
    const int n    = blockIdx.x;
    const int wave = threadIdx.x >> 6;
    const int lane = threadIdx.x & 63;
    if (lane >= 49) return;            // 49 bins per 7x7 output
    const int bin = lane;
    const int ph  = bin / 7;
    const int pw  = bin - ph * 7;
    const int cg  = blockIdx.y * 4 + wave;   // channel group 0..31

    // ---- per-RoI params (uniform within block) ----
    const float* r = rois + n * 6;
    const int   b     = (int)r[0];
    const float cx    = r[1] * 0.25f;
    const float cy    = r[2] * 0.25f;
    const float rw    = fmaxf(r[3] * 0.25f, 1.0f);
    const float rh    = fmaxf(r[4] * 0.25f, 1.0f);
    const float theta = r[5];
    const float bin_h = rh * (1.0f / 7.0f);
    const float bin_w = rw * (1.0f / 7.0f);

    const float ind_f = (theta * 8.0f) / 6.28318530717958647692f;
    const int   ind0  = (int)floorf(ind_f);
    const float l_var = ind_f - (float)ind0;
    const float r_var = 1.0f - l_var;
    const int   ind   = ((ind0 % 8) + 8) % 8;
    const float cos_t = cosf(theta);   // CLOCKWISE=false
    const float sin_t = sinf(theta);

    // ---- geometry for this bin's 4 samples: 16 corner offsets + 16 weights ----
    int   off[16];
    float wgt[16];
    #pragma unroll
    for (int s = 0; s < 4; ++s) {
        const int gy = s >> 1, gx = s & 1;
        const float yy = -rh * 0.5f + ((float)ph + ((float)gy + 0.5f) * 0.5f) * bin_h;
        const float xx = -rw * 0.5f + ((float)pw + ((float)gx + 0.5f) * 0.5f) * bin_w;
        const float y  = yy * cos_t - xx * sin_t + cy;
        const float x  = yy * sin_t + xx * cos_t + cx;
        const float valid =
            (y >= -1.0f && y <= 256.0f && x >= -1.0f && x <= 256.0f) ? 1.0f : 0.0f;
        const float yc = fmaxf(y, 0.0f);
        const float xc = fmaxf(x, 0.0f);
        const int y0 = min((int)floorf(yc), HH - 1);
        const int x0 = min((int)floorf(xc), WW - 1);
        const int y1 = min(y0 + 1, HH - 1);
        const int x1 = min(x0 + 1, WW - 1);
        const float ly = (y0 >= HH - 1) ? 0.0f : (yc - (float)y0);
        const float lx = (x0 >= WW - 1) ? 0.0f : (xc - (float)x0);
        const float hy = 1.0f - ly, hx = 1.0f - lx;
        const float sc = 0.25f * valid;            // fold sample mean + validity
        off[s * 4 + 0] = (y0 << 8) + x0;           // W = 256
        off[s * 4 + 1] = (y0 << 8) + x1;
        off[s * 4 + 2] = (y1 << 8) + x0;
        off[s * 4 + 3] = (y1 << 8) + x1;
        wgt[s * 4 + 0] = hy * hx * sc;
        wgt[s * 4 + 1] = hy * lx * sc;
        wgt[s * 4 + 2] = ly * hx * sc;
        wgt[s * 4 + 3] = ly * lx * sc;
    }

    // ---- pool the 8 orientation channels of this group ----
    const float* gbase = feats + (size_t)b * (CTOT * HW) + (size_t)(cg * 8) * HW;
    float acc[8];
    #pragma unroll
    for (int o = 0; o < 8; ++o) {
        const float* plane = gbase + (size_t)o * HW;
        float a = 0.0f;
        #pragma unroll
        for (int k = 0; k < 16; ++k)
            a += wgt[k] * plane[off[k]];
        acc[o] = a;
    }

    // ---- orientation mix in-register (static acc indices, dynamic store addr) ----
    float* obase = out + ((size_t)n * CTOT + (size_t)cg * 8) * 49 + bin;
    #pragma unroll
    for (int s = 0; s < 8; ++s) {
        const int o_out = (s + ind) & 7;
        const float val = r_var * acc[s] + l_var * acc[(s + 1) & 7];
        obase[o_out * 49] = val;
    }
}

extern "C" void kernel_launch(void* const* d_in, const int* in_sizes, int n_in,
                              void* d_out, int out_size, void* d_ws, size_t ws_size,
                              hipStream_t stream) {
    const float* feats = (const float*)d_in[0];
    const float* rois  = (const float*)d_in[1];
    float* out = (float*)d_out;
    const int n_rois = in_sizes[1] / 6;
    dim3 grid(n_rois, 8);
    riroi_rotated_kernel<<<grid, 256, 0, stream>>>(feats, rois, out);
}

// Round 3
// 386.022 us; speedup vs baseline: 1.3581x; 1.3581x over previous
//
#include <hip/hip_runtime.h>
#include <math.h>

#define HH 256
#define WW 256
#define CTOT 256
#define HW (HH * WW)
#define NBIN 49                    // 7*7
#define WPR  (32 * NBIN)           // work items per RoI: 32 cgroups * 49 bins = 1568

// One thread = one (roi, channel-group, bin). Processes the 8 orientation
// channels of its group with geometry held in registers (computed once).
// Corner pairs (x0, x0+1) fetched as one float2 -> 8 loads/channel.
// Channels processed in pairs -> 16 independent float2 loads batched per
// group for memory-level parallelism. No LDS, no __syncthreads.
__global__ __launch_bounds__(256) void riroi_rotated_kernel(
    const float* __restrict__ feats,   // (B, 256, 256, 256)
    const float* __restrict__ rois,    // (n_rois, 6)
    float* __restrict__ out,           // (n_rois, 256, 7, 7)
    int total)                         // n_rois * 1568
{
    const int g = blockIdx.x * 256 + threadIdx.x;
    if (g >= total) return;
    const int n   = g / WPR;
    const int rem = g - n * WPR;
    const int cg  = rem / NBIN;        // channel group 0..31
    const int bin = rem - cg * NBIN;   // 0..48  (bin-major: adjacent lanes = adjacent bins)
    const int ph  = bin / 7;
    const int pw  = bin - ph * 7;

    // ---- per-RoI params ----
    const float* r = rois + n * 6;
    const int   b     = (int)r[0];
    const float cx    = r[1] * 0.25f;
    const float cy    = r[2] * 0.25f;
    const float rw    = fmaxf(r[3] * 0.25f, 1.0f);
    const float rh    = fmaxf(r[4] * 0.25f, 1.0f);
    const float theta = r[5];
    const float bin_h = rh * (1.0f / 7.0f);
    const float bin_w = rw * (1.0f / 7.0f);

    const float ind_f = (theta * 8.0f) / 6.28318530717958647692f;
    const int   ind0  = (int)floorf(ind_f);
    const float l_var = ind_f - (float)ind0;
    const float r_var = 1.0f - l_var;
    const int   ind   = ((ind0 % 8) + 8) % 8;
    const float cos_t = cosf(theta);   // CLOCKWISE=false
    const float sin_t = sinf(theta);

    // ---- geometry: 4 samples -> per sample: 2 row offsets + 2 row wts + 2 col wts ----
    int   off0[4], off1[4];
    float rw0[4], rw1[4], cw0[4], cw1[4];
    #pragma unroll
    for (int s = 0; s < 4; ++s) {
        const int gy = s >> 1, gx = s & 1;
        const float yy = -rh * 0.5f + ((float)ph + ((float)gy + 0.5f) * 0.5f) * bin_h;
        const float xx = -rw * 0.5f + ((float)pw + ((float)gx + 0.5f) * 0.5f) * bin_w;
        const float y  = yy * cos_t - xx * sin_t + cy;
        const float x  = yy * sin_t + xx * cos_t + cx;
        const float valid =
            (y >= -1.0f && y <= 256.0f && x >= -1.0f && x <= 256.0f) ? 1.0f : 0.0f;
        const float yc = fmaxf(y, 0.0f);
        const float xc = fmaxf(x, 0.0f);
        const int y0 = min((int)floorf(yc), HH - 1);
        const int x0 = min((int)floorf(xc), WW - 1);
        const int y1 = min(y0 + 1, HH - 1);
        const float ly = (y0 >= HH - 1) ? 0.0f : (yc - (float)y0);
        const float lx = (x0 >= WW - 1) ? 0.0f : (xc - (float)x0);
        const float hy = 1.0f - ly, hx = 1.0f - lx;
        const float sc = 0.25f * valid;            // fold sample mean + validity
        const int   xb = min(x0, WW - 2);          // pair base column
        // pair covers (xb, xb+1); if x0==255 the wanted value sits in .y
        cw0[s]  = (x0 < WW - 1) ? hx : 0.0f;
        cw1[s]  = (x0 < WW - 1) ? lx : hx;
        rw0[s]  = hy * sc;
        rw1[s]  = ly * sc;
        off0[s] = (y0 << 8) + xb;
        off1[s] = (y1 << 8) + xb;
    }

    // ---- pool 8 orientation channels, 2 at a time (16 batched float2 loads) ----
    const float* gbase = feats + (size_t)b * (CTOT * HW) + (size_t)(cg * 8) * HW;
    float acc[8];
    #pragma unroll
    for (int o = 0; o < 8; o += 2) {
        const float* pA = gbase + (size_t)o * HW;
        const float* pB = pA + HW;
        float2 q[16];
        #pragma unroll
        for (int s = 0; s < 4; ++s) {
            q[s * 4 + 0] = *(const float2*)(pA + off0[s]);
            q[s * 4 + 1] = *(const float2*)(pA + off1[s]);
            q[s * 4 + 2] = *(const float2*)(pB + off0[s]);
            q[s * 4 + 3] = *(const float2*)(pB + off1[s]);
        }
        float a0 = 0.0f, a1 = 0.0f;
        #pragma unroll
        for (int s = 0; s < 4; ++s) {
            a0 += rw0[s] * (cw0[s] * q[s * 4 + 0].x + cw1[s] * q[s * 4 + 0].y)
                + rw1[s] * (cw0[s] * q[s * 4 + 1].x + cw1[s] * q[s * 4 + 1].y);
            a1 += rw0[s] * (cw0[s] * q[s * 4 + 2].x + cw1[s] * q[s * 4 + 2].y)
                + rw1[s] * (cw0[s] * q[s * 4 + 3].x + cw1[s] * q[s * 4 + 3].y);
        }
        acc[o]     = a0;
        acc[o + 1] = a1;
    }

    // ---- orientation mix in-register + nontemporal stores ----
    float* obase = out + ((size_t)n * CTOT + (size_t)(cg * 8)) * NBIN + bin;
    #pragma unroll
    for (int s = 0; s < 8; ++s) {
        const int o_out = (s + ind) & 7;
        const float val = r_var * acc[s] + l_var * acc[(s + 1) & 7];
        __builtin_nontemporal_store(val, obase + o_out * NBIN);
    }
}

extern "C" void kernel_launch(void* const* d_in, const int* in_sizes, int n_in,
                              void* d_out, int out_size, void* d_ws, size_t ws_size,
                              hipStream_t stream) {
    const float* feats = (const float*)d_in[0];
    const float* rois  = (const float*)d_in[1];
    float* out = (float*)d_out;
    const int n_rois = in_sizes[1] / 6;
    const int total  = n_rois * WPR;
    const int nblk   = (total + 255) / 256;
    riroi_rotated_kernel<<<nblk, 256, 0, stream>>>(feats, rois, out, total);
}

// Round 4
// 256.441 us; speedup vs baseline: 2.0443x; 1.5053x over previous
//
#include <hip/hip_runtime.h>
#include <hip/hip_fp16.h>
#include <math.h>

#define HH 256
#define WW 256
#define CTOT 256
#define HW (HH * WW)
#define NBIN 49

typedef __attribute__((ext_vector_type(8))) _Float16 half8;

// ---------- pass 1: (B,256,H,W) f32 -> (B,32,H,W,8) f16 orientation-interleaved ----------
__global__ __launch_bounds__(256) void convert_kernel(
    const float* __restrict__ feats, half8* __restrict__ wsf, int total /* B*32*HW */)
{
    const int g = blockIdx.x * 256 + threadIdx.x;
    if (g >= total) return;
    const int pix = g & (HW - 1);
    const int bc  = g >> 16;                 // b*32 + c
    const float* src = feats + ((size_t)bc * 8) * HW + pix;
    half8 v;
    #pragma unroll
    for (int o = 0; o < 8; ++o) v[o] = (_Float16)src[(size_t)o * HW];
    wsf[g] = v;
}

// ---------- pass 2: pooled gather; one thread = (cg, roi, bin), cg-major for L2 ----------
__global__ __launch_bounds__(256) void riroi_pool_f16(
    const half8* __restrict__ wsf,     // (B, 32, HW) of half8
    const float* __restrict__ rois,
    float* __restrict__ out,           // (n_rois, 256, 7, 7)
    int n_rois, int total)
{
    const int g = blockIdx.x * 256 + threadIdx.x;
    if (g >= total) return;
    const int per_cg = n_rois * NBIN;
    const int cg  = g / per_cg;              // slowest: channel group 0..31
    const int rem = g - cg * per_cg;
    const int n   = rem / NBIN;
    const int bin = rem - n * NBIN;
    const int ph  = bin / 7;
    const int pw  = bin - ph * 7;

    const float* r = rois + n * 6;
    const int   b     = (int)r[0];
    const float cx    = r[1] * 0.25f;
    const float cy    = r[2] * 0.25f;
    const float rwv   = fmaxf(r[3] * 0.25f, 1.0f);
    const float rhv   = fmaxf(r[4] * 0.25f, 1.0f);
    const float theta = r[5];
    const float bin_h = rhv * (1.0f / 7.0f);
    const float bin_w = rwv * (1.0f / 7.0f);

    const float ind_f = (theta * 8.0f) / 6.28318530717958647692f;
    const int   ind0  = (int)floorf(ind_f);
    const float l_var = ind_f - (float)ind0;
    const float r_var = 1.0f - l_var;
    const int   ind   = ((ind0 % 8) + 8) % 8;
    const float cos_t = cosf(theta);
    const float sin_t = sinf(theta);

    int   off0[4], off1[4];
    float rw0[4], rw1[4], cw0[4], cw1[4];
    #pragma unroll
    for (int s = 0; s < 4; ++s) {
        const int gy = s >> 1, gx = s & 1;
        const float yy = -rhv * 0.5f + ((float)ph + ((float)gy + 0.5f) * 0.5f) * bin_h;
        const float xx = -rwv * 0.5f + ((float)pw + ((float)gx + 0.5f) * 0.5f) * bin_w;
        const float y  = yy * cos_t - xx * sin_t + cy;
        const float x  = yy * sin_t + xx * cos_t + cx;
        const float valid =
            (y >= -1.0f && y <= 256.0f && x >= -1.0f && x <= 256.0f) ? 1.0f : 0.0f;
        const float yc = fmaxf(y, 0.0f);
        const float xc = fmaxf(x, 0.0f);
        const int y0 = min((int)floorf(yc), HH - 1);
        const int x0 = min((int)floorf(xc), WW - 1);
        const int y1 = min(y0 + 1, HH - 1);
        const float ly = (y0 >= HH - 1) ? 0.0f : (yc - (float)y0);
        const float lx = (x0 >= WW - 1) ? 0.0f : (xc - (float)x0);
        const float hy = 1.0f - ly, hx = 1.0f - lx;
        const float sc = 0.25f * valid;
        const int   xb = min(x0, WW - 2);          // pair base (xb, xb+1) always in-bounds
        cw0[s]  = (x0 < WW - 1) ? hx : 0.0f;       // x0==255 -> value sits at .y slot
        cw1[s]  = (x0 < WW - 1) ? lx : hx;
        rw0[s]  = hy * sc;
        rw1[s]  = ly * sc;
        off0[s] = (y0 << 8) + xb;
        off1[s] = (y1 << 8) + xb;
    }

    const half8* base = wsf + (size_t)(b * 32 + cg) * HW;

    // 16 independent 16B loads, batched for MLP
    half8 q[16];
    #pragma unroll
    for (int s = 0; s < 4; ++s) {
        q[s * 4 + 0] = base[off0[s]];
        q[s * 4 + 1] = base[off0[s] + 1];
        q[s * 4 + 2] = base[off1[s]];
        q[s * 4 + 3] = base[off1[s] + 1];
    }

    float acc[8] = {0,0,0,0,0,0,0,0};
    #pragma unroll
    for (int s = 0; s < 4; ++s) {
        const float w00 = rw0[s] * cw0[s];
        const float w01 = rw0[s] * cw1[s];
        const float w10 = rw1[s] * cw0[s];
        const float w11 = rw1[s] * cw1[s];
        const half8 a = q[s * 4 + 0], c = q[s * 4 + 1];
        const half8 d = q[s * 4 + 2], e = q[s * 4 + 3];
        #pragma unroll
        for (int o = 0; o < 8; ++o)
            acc[o] += w00 * (float)a[o] + w01 * (float)c[o]
                    + w10 * (float)d[o] + w11 * (float)e[o];
    }

    float* obase = out + ((size_t)n * CTOT + (size_t)(cg * 8)) * NBIN + bin;
    #pragma unroll
    for (int s = 0; s < 8; ++s) {
        const int o_out = (s + ind) & 7;
        const float val = r_var * acc[s] + l_var * acc[(s + 1) & 7];
        __builtin_nontemporal_store(val, obase + o_out * NBIN);
    }
}

// ---------- fallback (R3 kernel) if workspace too small ----------
__global__ __launch_bounds__(256) void riroi_rotated_fallback(
    const float* __restrict__ feats, const float* __restrict__ rois,
    float* __restrict__ out, int total)
{
    const int g = blockIdx.x * 256 + threadIdx.x;
    if (g >= total) return;
    const int wpr = 32 * NBIN;
    const int n   = g / wpr;
    const int rem = g - n * wpr;
    const int cg  = rem / NBIN;
    const int bin = rem - cg * NBIN;
    const int ph  = bin / 7;
    const int pw  = bin - ph * 7;
    const float* r = rois + n * 6;
    const int   b     = (int)r[0];
    const float cx    = r[1] * 0.25f;
    const float cy    = r[2] * 0.25f;
    const float rwv   = fmaxf(r[3] * 0.25f, 1.0f);
    const float rhv   = fmaxf(r[4] * 0.25f, 1.0f);
    const float theta = r[5];
    const float bin_h = rhv * (1.0f / 7.0f);
    const float bin_w = rwv * (1.0f / 7.0f);
    const float ind_f = (theta * 8.0f) / 6.28318530717958647692f;
    const int   ind0  = (int)floorf(ind_f);
    const float l_var = ind_f - (float)ind0;
    const float r_var = 1.0f - l_var;
    const int   ind   = ((ind0 % 8) + 8) % 8;
    const float cos_t = cosf(theta);
    const float sin_t = sinf(theta);
    int   off0[4], off1[4];
    float rw0[4], rw1[4], cw0[4], cw1[4];
    #pragma unroll
    for (int s = 0; s < 4; ++s) {
        const int gy = s >> 1, gx = s & 1;
        const float yy = -rhv * 0.5f + ((float)ph + ((float)gy + 0.5f) * 0.5f) * bin_h;
        const float xx = -rwv * 0.5f + ((float)pw + ((float)gx + 0.5f) * 0.5f) * bin_w;
        const float y  = yy * cos_t - xx * sin_t + cy;
        const float x  = yy * sin_t + xx * cos_t + cx;
        const float valid =
            (y >= -1.0f && y <= 256.0f && x >= -1.0f && x <= 256.0f) ? 1.0f : 0.0f;
        const float yc = fmaxf(y, 0.0f);
        const float xc = fmaxf(x, 0.0f);
        const int y0 = min((int)floorf(yc), HH - 1);
        const int x0 = min((int)floorf(xc), WW - 1);
        const int y1 = min(y0 + 1, HH - 1);
        const float ly = (y0 >= HH - 1) ? 0.0f : (yc - (float)y0);
        const float lx = (x0 >= WW - 1) ? 0.0f : (xc - (float)x0);
        const float hy = 1.0f - ly, hx = 1.0f - lx;
        const float sc = 0.25f * valid;
        const int   xb = min(x0, WW - 2);
        cw0[s]  = (x0 < WW - 1) ? hx : 0.0f;
        cw1[s]  = (x0 < WW - 1) ? lx : hx;
        rw0[s]  = hy * sc;
        rw1[s]  = ly * sc;
        off0[s] = (y0 << 8) + xb;
        off1[s] = (y1 << 8) + xb;
    }
    const float* gbase = feats + (size_t)b * (CTOT * HW) + (size_t)(cg * 8) * HW;
    float acc[8];
    #pragma unroll
    for (int o = 0; o < 8; o += 2) {
        const float* pA = gbase + (size_t)o * HW;
        const float* pB = pA + HW;
        float2 q[16];
        #pragma unroll
        for (int s = 0; s < 4; ++s) {
            q[s * 4 + 0] = *(const float2*)(pA + off0[s]);
            q[s * 4 + 1] = *(const float2*)(pA + off1[s]);
            q[s * 4 + 2] = *(const float2*)(pB + off0[s]);
            q[s * 4 + 3] = *(const float2*)(pB + off1[s]);
        }
        float a0 = 0.0f, a1 = 0.0f;
        #pragma unroll
        for (int s = 0; s < 4; ++s) {
            a0 += rw0[s] * (cw0[s] * q[s * 4 + 0].x + cw1[s] * q[s * 4 + 0].y)
                + rw1[s] * (cw0[s] * q[s * 4 + 1].x + cw1[s] * q[s * 4 + 1].y);
            a1 += rw0[s] * (cw0[s] * q[s * 4 + 2].x + cw1[s] * q[s * 4 + 2].y)
                + rw1[s] * (cw0[s] * q[s * 4 + 3].x + cw1[s] * q[s * 4 + 3].y);
        }
        acc[o] = a0; acc[o + 1] = a1;
    }
    float* obase = out + ((size_t)n * CTOT + (size_t)(cg * 8)) * NBIN + bin;
    #pragma unroll
    for (int s = 0; s < 8; ++s) {
        const int o_out = (s + ind) & 7;
        __builtin_nontemporal_store(r_var * acc[s] + l_var * acc[(s + 1) & 7],
                                    obase + o_out * NBIN);
    }
}

extern "C" void kernel_launch(void* const* d_in, const int* in_sizes, int n_in,
                              void* d_out, int out_size, void* d_ws, size_t ws_size,
                              hipStream_t stream) {
    const float* feats = (const float*)d_in[0];
    const float* rois  = (const float*)d_in[1];
    float* out = (float*)d_out;
    const int n_rois = in_sizes[1] / 6;
    const int B      = in_sizes[0] / (CTOT * HW);
    const int total  = n_rois * 32 * NBIN;
    const size_t ws_need = (size_t)B * 32 * HW * sizeof(half8);

    if (ws_size >= ws_need) {
        half8* wsf = (half8*)d_ws;
        const int tc = B * 32 * HW;
        convert_kernel<<<(tc + 255) / 256, 256, 0, stream>>>(feats, wsf, tc);
        riroi_pool_f16<<<(total + 255) / 256, 256, 0, stream>>>(wsf, rois, out, n_rois, total);
    } else {
        riroi_rotated_fallback<<<(total + 255) / 256, 256, 0, stream>>>(feats, rois, out, total);
    }
}

// Round 5
// 240.252 us; speedup vs baseline: 2.1821x; 1.0674x over previous
//
#include <hip/hip_runtime.h>
#include <hip/hip_fp16.h>
#include <math.h>

#define HH 256
#define WW 256
#define CTOT 256
#define HW (HH * WW)
#define NBIN 49

typedef __attribute__((ext_vector_type(8))) _Float16 half8;

// ---------- pass 1: (B,256,H,W) f32 -> (B,32,H,W,8) f16 orientation-interleaved ----------
__global__ __launch_bounds__(256) void convert_kernel(
    const float* __restrict__ feats, half8* __restrict__ wsf, int total /* B*32*HW */)
{
    const int g = blockIdx.x * 256 + threadIdx.x;
    if (g >= total) return;
    const int pix = g & (HW - 1);
    const int bc  = g >> 16;                 // b*32 + c
    const float* src = feats + ((size_t)bc * 8) * HW + pix;
    half8 v;
    #pragma unroll
    for (int o = 0; o < 8; ++o) v[o] = (_Float16)src[(size_t)o * HW];
    wsf[g] = v;
}

// ---------- pass 2: one thread = (cg, roi, bin, sample-row gy) ----------
// Lane pairs (even,odd) share (cg,roi,bin): even does gy=0 samples, odd gy=1.
// 8 independent 16B gathers per thread; partial sums combined via shfl_xor(1).
__global__ __launch_bounds__(256) void riroi_pool_f16_v2(
    const half8* __restrict__ wsf,     // (B, 32, HW) of half8
    const float* __restrict__ rois,
    float* __restrict__ out,           // (n_rois, 256, 7, 7)
    int per_cg2)                       // n_rois * 49 * 2
{
    const int h = blockIdx.x * 256 + threadIdx.x;
    if (h >= per_cg2) return;
    const int cg  = blockIdx.y;        // channel group 0..31 (slowest -> L2 blocking)
    const int sh  = h & 1;             // sample row gy
    const int t   = h >> 1;
    const int n   = t / NBIN;
    const int bin = t - n * NBIN;
    const int ph  = bin / 7;
    const int pw  = bin - ph * 7;

    const float* r = rois + n * 6;
    const int   b     = (int)r[0];
    const float cx    = r[1] * 0.25f;
    const float cy    = r[2] * 0.25f;
    const float rwv   = fmaxf(r[3] * 0.25f, 1.0f);
    const float rhv   = fmaxf(r[4] * 0.25f, 1.0f);
    const float theta = r[5];
    const float bin_h = rhv * (1.0f / 7.0f);
    const float bin_w = rwv * (1.0f / 7.0f);

    const float ind_f = (theta * 8.0f) / 6.28318530717958647692f;
    const int   ind0  = (int)floorf(ind_f);
    const float l_var = ind_f - (float)ind0;
    const float r_var = 1.0f - l_var;
    const int   ind   = ((ind0 % 8) + 8) % 8;
    const float cos_t = cosf(theta);   // CLOCKWISE=false
    const float sin_t = sinf(theta);

    // ---- geometry for this thread's 2 samples (gy=sh, gx=0,1) ----
    int   off0[2], off1[2];
    float rw0[2], rw1[2], cw0[2], cw1[2];
    const float yy = -rhv * 0.5f + ((float)ph + ((float)sh + 0.5f) * 0.5f) * bin_h;
    #pragma unroll
    for (int j = 0; j < 2; ++j) {
        const float xx = -rwv * 0.5f + ((float)pw + ((float)j + 0.5f) * 0.5f) * bin_w;
        const float y  = yy * cos_t - xx * sin_t + cy;
        const float x  = yy * sin_t + xx * cos_t + cx;
        const float valid =
            (y >= -1.0f && y <= 256.0f && x >= -1.0f && x <= 256.0f) ? 1.0f : 0.0f;
        const float yc = fmaxf(y, 0.0f);
        const float xc = fmaxf(x, 0.0f);
        const int y0 = min((int)floorf(yc), HH - 1);
        const int x0 = min((int)floorf(xc), WW - 1);
        const int y1 = min(y0 + 1, HH - 1);
        const float ly = (y0 >= HH - 1) ? 0.0f : (yc - (float)y0);
        const float lx = (x0 >= WW - 1) ? 0.0f : (xc - (float)x0);
        const float hy = 1.0f - ly, hx = 1.0f - lx;
        const float sc = 0.25f * valid;
        const int   xb = min(x0, WW - 2);          // pair base (xb, xb+1) in-bounds
        cw0[j]  = (x0 < WW - 1) ? hx : 0.0f;       // x0==255 -> value sits at .y slot
        cw1[j]  = (x0 < WW - 1) ? lx : hx;
        rw0[j]  = hy * sc;
        rw1[j]  = ly * sc;
        off0[j] = (y0 << 8) + xb;
        off1[j] = (y1 << 8) + xb;
    }

    const half8* base = wsf + (size_t)(b * 32 + cg) * HW;

    // 8 independent 16B loads, batched for MLP
    half8 q[8];
    #pragma unroll
    for (int j = 0; j < 2; ++j) {
        q[j * 4 + 0] = base[off0[j]];
        q[j * 4 + 1] = base[off0[j] + 1];
        q[j * 4 + 2] = base[off1[j]];
        q[j * 4 + 3] = base[off1[j] + 1];
    }

    float acc[8] = {0,0,0,0,0,0,0,0};
    #pragma unroll
    for (int j = 0; j < 2; ++j) {
        const float w00 = rw0[j] * cw0[j];
        const float w01 = rw0[j] * cw1[j];
        const float w10 = rw1[j] * cw0[j];
        const float w11 = rw1[j] * cw1[j];
        const half8 a = q[j * 4 + 0], c = q[j * 4 + 1];
        const half8 d = q[j * 4 + 2], e = q[j * 4 + 3];
        #pragma unroll
        for (int o = 0; o < 8; ++o)
            acc[o] += w00 * (float)a[o] + w01 * (float)c[o]
                    + w10 * (float)d[o] + w11 * (float)e[o];
    }

    // combine the two sample-rows (lane pairs are always co-active)
    #pragma unroll
    for (int o = 0; o < 8; ++o)
        acc[o] += __shfl_xor(acc[o], 1, 64);

    // ---- orientation mix; even lane stores s=0..3, odd lane s=4..7 ----
    float* obase = out + ((size_t)n * CTOT + (size_t)(cg * 8)) * NBIN + bin;
    if (sh == 0) {
        #pragma unroll
        for (int k = 0; k < 4; ++k) {
            const int o_out = (k + ind) & 7;
            const float val = r_var * acc[k] + l_var * acc[k + 1];
            __builtin_nontemporal_store(val, obase + o_out * NBIN);
        }
    } else {
        #pragma unroll
        for (int k = 4; k < 8; ++k) {
            const int o_out = (k + ind) & 7;
            const float val = r_var * acc[k] + l_var * acc[(k + 1) & 7];
            __builtin_nontemporal_store(val, obase + o_out * NBIN);
        }
    }
}

// ---------- fallback if workspace too small ----------
__global__ __launch_bounds__(256) void riroi_rotated_fallback(
    const float* __restrict__ feats, const float* __restrict__ rois,
    float* __restrict__ out, int total)
{
    const int g = blockIdx.x * 256 + threadIdx.x;
    if (g >= total) return;
    const int wpr = 32 * NBIN;
    const int n   = g / wpr;
    const int rem = g - n * wpr;
    const int cg  = rem / NBIN;
    const int bin = rem - cg * NBIN;
    const int ph  = bin / 7;
    const int pw  = bin - ph * 7;
    const float* r = rois + n * 6;
    const int   b     = (int)r[0];
    const float cx    = r[1] * 0.25f;
    const float cy    = r[2] * 0.25f;
    const float rwv   = fmaxf(r[3] * 0.25f, 1.0f);
    const float rhv   = fmaxf(r[4] * 0.25f, 1.0f);
    const float theta = r[5];
    const float bin_h = rhv * (1.0f / 7.0f);
    const float bin_w = rwv * (1.0f / 7.0f);
    const float ind_f = (theta * 8.0f) / 6.28318530717958647692f;
    const int   ind0  = (int)floorf(ind_f);
    const float l_var = ind_f - (float)ind0;
    const float r_var = 1.0f - l_var;
    const int   ind   = ((ind0 % 8) + 8) % 8;
    const float cos_t = cosf(theta);
    const float sin_t = sinf(theta);
    int   off0[4], off1[4];
    float rw0[4], rw1[4], cw0[4], cw1[4];
    #pragma unroll
    for (int s = 0; s < 4; ++s) {
        const int gy = s >> 1, gx = s & 1;
        const float yy = -rhv * 0.5f + ((float)ph + ((float)gy + 0.5f) * 0.5f) * bin_h;
        const float xx = -rwv * 0.5f + ((float)pw + ((float)gx + 0.5f) * 0.5f) * bin_w;
        const float y  = yy * cos_t - xx * sin_t + cy;
        const float x  = yy * sin_t + xx * cos_t + cx;
        const float valid =
            (y >= -1.0f && y <= 256.0f && x >= -1.0f && x <= 256.0f) ? 1.0f : 0.0f;
        const float yc = fmaxf(y, 0.0f);
        const float xc = fmaxf(x, 0.0f);
        const int y0 = min((int)floorf(yc), HH - 1);
        const int x0 = min((int)floorf(xc), WW - 1);
        const int y1 = min(y0 + 1, HH - 1);
        const float ly = (y0 >= HH - 1) ? 0.0f : (yc - (float)y0);
        const float lx = (x0 >= WW - 1) ? 0.0f : (xc - (float)x0);
        const float hy = 1.0f - ly, hx = 1.0f - lx;
        const float sc = 0.25f * valid;
        const int   xb = min(x0, WW - 2);
        cw0[s]  = (x0 < WW - 1) ? hx : 0.0f;
        cw1[s]  = (x0 < WW - 1) ? lx : hx;
        rw0[s]  = hy * sc;
        rw1[s]  = ly * sc;
        off0[s] = (y0 << 8) + xb;
        off1[s] = (y1 << 8) + xb;
    }
    const float* gbase = feats + (size_t)b * (CTOT * HW) + (size_t)(cg * 8) * HW;
    float acc[8];
    #pragma unroll
    for (int o = 0; o < 8; o += 2) {
        const float* pA = gbase + (size_t)o * HW;
        const float* pB = pA + HW;
        float2 q[16];
        #pragma unroll
        for (int s = 0; s < 4; ++s) {
            q[s * 4 + 0] = *(const float2*)(pA + off0[s]);
            q[s * 4 + 1] = *(const float2*)(pA + off1[s]);
            q[s * 4 + 2] = *(const float2*)(pB + off0[s]);
            q[s * 4 + 3] = *(const float2*)(pB + off1[s]);
        }
        float a0 = 0.0f, a1 = 0.0f;
        #pragma unroll
        for (int s = 0; s < 4; ++s) {
            a0 += rw0[s] * (cw0[s] * q[s * 4 + 0].x + cw1[s] * q[s * 4 + 0].y)
                + rw1[s] * (cw0[s] * q[s * 4 + 1].x + cw1[s] * q[s * 4 + 1].y);
            a1 += rw0[s] * (cw0[s] * q[s * 4 + 2].x + cw1[s] * q[s * 4 + 2].y)
                + rw1[s] * (cw0[s] * q[s * 4 + 3].x + cw1[s] * q[s * 4 + 3].y);
        }
        acc[o] = a0; acc[o + 1] = a1;
    }
    float* obase = out + ((size_t)n * CTOT + (size_t)(cg * 8)) * NBIN + bin;
    #pragma unroll
    for (int s = 0; s < 8; ++s) {
        const int o_out = (s + ind) & 7;
        __builtin_nontemporal_store(r_var * acc[s] + l_var * acc[(s + 1) & 7],
                                    obase + o_out * NBIN);
    }
}

extern "C" void kernel_launch(void* const* d_in, const int* in_sizes, int n_in,
                              void* d_out, int out_size, void* d_ws, size_t ws_size,
                              hipStream_t stream) {
    const float* feats = (const float*)d_in[0];
    const float* rois  = (const float*)d_in[1];
    float* out = (float*)d_out;
    const int n_rois = in_sizes[1] / 6;
    const int B      = in_sizes[0] / (CTOT * HW);
    const size_t ws_need = (size_t)B * 32 * HW * sizeof(half8);

    if (ws_size >= ws_need) {
        half8* wsf = (half8*)d_ws;
        const int tc = B * 32 * HW;
        convert_kernel<<<(tc + 255) / 256, 256, 0, stream>>>(feats, wsf, tc);
        const int per_cg2 = n_rois * NBIN * 2;
        dim3 grid((per_cg2 + 255) / 256, 32);
        riroi_pool_f16_v2<<<grid, 256, 0, stream>>>(wsf, rois, out, per_cg2);
    } else {
        const int total = n_rois * 32 * NBIN;
        riroi_rotated_fallback<<<(total + 255) / 256, 256, 0, stream>>>(feats, rois, out, total);
    }
}

// Round 7
// 238.998 us; speedup vs baseline: 2.1935x; 1.0052x over previous
//
#include <hip/hip_runtime.h>
#include <hip/hip_fp16.h>
#include <math.h>

#define HH 256
#define WW 256
#define CTOT 256
#define HW (HH * WW)
#define NBIN 49

typedef __attribute__((ext_vector_type(8))) _Float16 half8;
typedef __attribute__((ext_vector_type(4))) float fvec4;

// ---------- pass 1: (B,256,H,W) f32 -> (B,32,H,W,8) f16 orientation-interleaved ----------
// One thread = 4 consecutive pixels of one channel-group: 8 fvec4 NT loads -> 4 half8 stores.
__global__ __launch_bounds__(256) void convert_kernel_v2(
    const float* __restrict__ feats, half8* __restrict__ wsf, int total4 /* B*32*HW/4 */)
{
    const int g = blockIdx.x * 256 + threadIdx.x;
    if (g >= total4) return;
    const int pix = (g & 16383) << 2;        // HW/4 = 16384
    const int bc  = g >> 14;                 // b*32 + c
    const float* src = feats + ((size_t)bc * 8) * HW + pix;
    fvec4 v[8];
    #pragma unroll
    for (int o = 0; o < 8; ++o)
        v[o] = __builtin_nontemporal_load((const fvec4*)(src + (size_t)o * HW));
    half8* dst = wsf + (size_t)bc * HW + pix;
    #pragma unroll
    for (int j = 0; j < 4; ++j) {
        half8 h;
        h[0] = (_Float16)v[0][j]; h[1] = (_Float16)v[1][j];
        h[2] = (_Float16)v[2][j]; h[3] = (_Float16)v[3][j];
        h[4] = (_Float16)v[4][j]; h[5] = (_Float16)v[5][j];
        h[6] = (_Float16)v[6][j]; h[7] = (_Float16)v[7][j];
        dst[j] = h;
    }
}

// ---------- pass 2: one thread = (cg, roi, bin, sample s) ----------
// Lane quads (aligned) share (cg,roi,bin); butterfly-combine 4 samples; each
// lane stores 2 of the 8 orientation-mixed outputs (static acc indices).
__global__ __launch_bounds__(256) void riroi_pool_f16_v3(
    const half8* __restrict__ wsf,     // (B, 32, HW) of half8
    const float* __restrict__ rois,
    float* __restrict__ out,           // (n_rois, 256, 7, 7)
    int per_cg4)                       // n_rois * 49 * 4
{
    const int h = blockIdx.x * 256 + threadIdx.x;
    if (h >= per_cg4) return;
    const int cg  = blockIdx.y;        // channel group 0..31 (slowest -> L2 blocking)
    const int s   = h & 3;             // sample: gy = s>>1, gx = s&1
    const int t   = h >> 2;
    const int n   = t / NBIN;
    const int bin = t - n * NBIN;
    const int ph  = bin / 7;
    const int pw  = bin - ph * 7;

    const float* r = rois + n * 6;
    const int   b     = (int)r[0];
    const float cx    = r[1] * 0.25f;
    const float cy    = r[2] * 0.25f;
    const float rwv   = fmaxf(r[3] * 0.25f, 1.0f);
    const float rhv   = fmaxf(r[4] * 0.25f, 1.0f);
    const float theta = r[5];
    const float bin_h = rhv * (1.0f / 7.0f);
    const float bin_w = rwv * (1.0f / 7.0f);

    const float ind_f = (theta * 8.0f) / 6.28318530717958647692f;
    const int   ind0  = (int)floorf(ind_f);
    const float l_var = ind_f - (float)ind0;
    const float r_var = 1.0f - l_var;
    const int   ind   = ((ind0 % 8) + 8) % 8;
    const float cos_t = cosf(theta);   // CLOCKWISE=false
    const float sin_t = sinf(theta);

    // ---- geometry for this thread's single sample ----
    const int gy = s >> 1, gx = s & 1;
    const float yy = -rhv * 0.5f + ((float)ph + ((float)gy + 0.5f) * 0.5f) * bin_h;
    const float xx = -rwv * 0.5f + ((float)pw + ((float)gx + 0.5f) * 0.5f) * bin_w;
    const float y  = yy * cos_t - xx * sin_t + cy;
    const float x  = yy * sin_t + xx * cos_t + cx;
    const float valid =
        (y >= -1.0f && y <= 256.0f && x >= -1.0f && x <= 256.0f) ? 1.0f : 0.0f;
    const float yc = fmaxf(y, 0.0f);
    const float xc = fmaxf(x, 0.0f);
    const int y0 = min((int)floorf(yc), HH - 1);
    const int x0 = min((int)floorf(xc), WW - 1);
    const int y1 = min(y0 + 1, HH - 1);
    const float ly = (y0 >= HH - 1) ? 0.0f : (yc - (float)y0);
    const float lx = (x0 >= WW - 1) ? 0.0f : (xc - (float)x0);
    const float hy = 1.0f - ly, hx = 1.0f - lx;
    const float sc = 0.25f * valid;            // fold sample mean + validity
    const int   xb = min(x0, WW - 2);          // pair base (xb, xb+1) in-bounds
    const float cw0 = (x0 < WW - 1) ? hx : 0.0f;   // x0==255 -> value sits at .y slot
    const float cw1 = (x0 < WW - 1) ? lx : hx;
    const float w00 = hy * sc * cw0;
    const float w01 = hy * sc * cw1;
    const float w10 = ly * sc * cw0;
    const float w11 = ly * sc * cw1;
    const int off0 = (y0 << 8) + xb;
    const int off1 = (y1 << 8) + xb;

    const half8* base = wsf + (size_t)(b * 32 + cg) * HW;

    // 4 independent 16B loads
    const half8 q0 = base[off0];
    const half8 q1 = base[off0 + 1];
    const half8 q2 = base[off1];
    const half8 q3 = base[off1 + 1];

    float acc[8];
    #pragma unroll
    for (int o = 0; o < 8; ++o)
        acc[o] = w00 * (float)q0[o] + w01 * (float)q1[o]
               + w10 * (float)q2[o] + w11 * (float)q3[o];

    // combine the 4 samples of this bin (lane quads aligned & co-active)
    #pragma unroll
    for (int o = 0; o < 8; ++o) {
        acc[o] += __shfl_xor(acc[o], 1, 64);
        acc[o] += __shfl_xor(acc[o], 2, 64);
    }

    // ---- orientation mix; lane s stores outputs k=2s, 2s+1 (static indices) ----
    float* obase = out + ((size_t)n * CTOT + (size_t)(cg * 8)) * NBIN + bin;
    switch (s) {
    case 0:
        __builtin_nontemporal_store(r_var * acc[0] + l_var * acc[1], obase + (((0 + ind) & 7) * NBIN));
        __builtin_nontemporal_store(r_var * acc[1] + l_var * acc[2], obase + (((1 + ind) & 7) * NBIN));
        break;
    case 1:
        __builtin_nontemporal_store(r_var * acc[2] + l_var * acc[3], obase + (((2 + ind) & 7) * NBIN));
        __builtin_nontemporal_store(r_var * acc[3] + l_var * acc[4], obase + (((3 + ind) & 7) * NBIN));
        break;
    case 2:
        __builtin_nontemporal_store(r_var * acc[4] + l_var * acc[5], obase + (((4 + ind) & 7) * NBIN));
        __builtin_nontemporal_store(r_var * acc[5] + l_var * acc[6], obase + (((5 + ind) & 7) * NBIN));
        break;
    default:
        __builtin_nontemporal_store(r_var * acc[6] + l_var * acc[7], obase + (((6 + ind) & 7) * NBIN));
        __builtin_nontemporal_store(r_var * acc[7] + l_var * acc[0], obase + (((7 + ind) & 7) * NBIN));
        break;
    }
}

// ---------- fallback if workspace too small ----------
__global__ __launch_bounds__(256) void riroi_rotated_fallback(
    const float* __restrict__ feats, const float* __restrict__ rois,
    float* __restrict__ out, int total)
{
    const int g = blockIdx.x * 256 + threadIdx.x;
    if (g >= total) return;
    const int wpr = 32 * NBIN;
    const int n   = g / wpr;
    const int rem = g - n * wpr;
    const int cg  = rem / NBIN;
    const int bin = rem - cg * NBIN;
    const int ph  = bin / 7;
    const int pw  = bin - ph * 7;
    const float* r = rois + n * 6;
    const int   b     = (int)r[0];
    const float cx    = r[1] * 0.25f;
    const float cy    = r[2] * 0.25f;
    const float rwv   = fmaxf(r[3] * 0.25f, 1.0f);
    const float rhv   = fmaxf(r[4] * 0.25f, 1.0f);
    const float theta = r[5];
    const float bin_h = rhv * (1.0f / 7.0f);
    const float bin_w = rwv * (1.0f / 7.0f);
    const float ind_f = (theta * 8.0f) / 6.28318530717958647692f;
    const int   ind0  = (int)floorf(ind_f);
    const float l_var = ind_f - (float)ind0;
    const float r_var = 1.0f - l_var;
    const int   ind   = ((ind0 % 8) + 8) % 8;
    const float cos_t = cosf(theta);
    const float sin_t = sinf(theta);
    int   off0[4], off1[4];
    float rw0[4], rw1[4], cw0[4], cw1[4];
    #pragma unroll
    for (int s = 0; s < 4; ++s) {
        const int gy = s >> 1, gx = s & 1;
        const float yy = -rhv * 0.5f + ((float)ph + ((float)gy + 0.5f) * 0.5f) * bin_h;
        const float xx = -rwv * 0.5f + ((float)pw + ((float)gx + 0.5f) * 0.5f) * bin_w;
        const float y  = yy * cos_t - xx * sin_t + cy;
        const float x  = yy * sin_t + xx * cos_t + cx;
        const float valid =
            (y >= -1.0f && y <= 256.0f && x >= -1.0f && x <= 256.0f) ? 1.0f : 0.0f;
        const float yc = fmaxf(y, 0.0f);
        const float xc = fmaxf(x, 0.0f);
        const int y0 = min((int)floorf(yc), HH - 1);
        const int x0 = min((int)floorf(xc), WW - 1);
        const int y1 = min(y0 + 1, HH - 1);
        const float ly = (y0 >= HH - 1) ? 0.0f : (yc - (float)y0);
        const float lx = (x0 >= WW - 1) ? 0.0f : (xc - (float)x0);
        const float hy = 1.0f - ly, hx = 1.0f - lx;
        const float sc = 0.25f * valid;
        const int   xb = min(x0, WW - 2);
        cw0[s]  = (x0 < WW - 1) ? hx : 0.0f;
        cw1[s]  = (x0 < WW - 1) ? lx : hx;
        rw0[s]  = hy * sc;
        rw1[s]  = ly * sc;
        off0[s] = (y0 << 8) + xb;
        off1[s] = (y1 << 8) + xb;
    }
    const float* gbase = feats + (size_t)b * (CTOT * HW) + (size_t)(cg * 8) * HW;
    float acc[8];
    #pragma unroll
    for (int o = 0; o < 8; o += 2) {
        const float* pA = gbase + (size_t)o * HW;
        const float* pB = pA + HW;
        float2 q[16];
        #pragma unroll
        for (int s = 0; s < 4; ++s) {
            q[s * 4 + 0] = *(const float2*)(pA + off0[s]);
            q[s * 4 + 1] = *(const float2*)(pA + off1[s]);
            q[s * 4 + 2] = *(const float2*)(pB + off0[s]);
            q[s * 4 + 3] = *(const float2*)(pB + off1[s]);
        }
        float a0 = 0.0f, a1 = 0.0f;
        #pragma unroll
        for (int s = 0; s < 4; ++s) {
            a0 += rw0[s] * (cw0[s] * q[s * 4 + 0].x + cw1[s] * q[s * 4 + 0].y)
                + rw1[s] * (cw0[s] * q[s * 4 + 1].x + cw1[s] * q[s * 4 + 1].y);
            a1 += rw0[s] * (cw0[s] * q[s * 4 + 2].x + cw1[s] * q[s * 4 + 2].y)
                + rw1[s] * (cw0[s] * q[s * 4 + 3].x + cw1[s] * q[s * 4 + 3].y);
        }
        acc[o] = a0; acc[o + 1] = a1;
    }
    float* obase = out + ((size_t)n * CTOT + (size_t)(cg * 8)) * NBIN + bin;
    #pragma unroll
    for (int s = 0; s < 8; ++s) {
        const int o_out = (s + ind) & 7;
        __builtin_nontemporal_store(r_var * acc[s] + l_var * acc[(s + 1) & 7],
                                    obase + o_out * NBIN);
    }
}

extern "C" void kernel_launch(void* const* d_in, const int* in_sizes, int n_in,
                              void* d_out, int out_size, void* d_ws, size_t ws_size,
                              hipStream_t stream) {
    const float* feats = (const float*)d_in[0];
    const float* rois  = (const float*)d_in[1];
    float* out = (float*)d_out;
    const int n_rois = in_sizes[1] / 6;
    const int B      = in_sizes[0] / (CTOT * HW);
    const size_t ws_need = (size_t)B * 32 * HW * sizeof(half8);

    if (ws_size >= ws_need) {
        half8* wsf = (half8*)d_ws;
        const int tc4 = B * 32 * HW / 4;
        convert_kernel_v2<<<(tc4 + 255) / 256, 256, 0, stream>>>(feats, wsf, tc4);
        const int per_cg4 = n_rois * NBIN * 4;
        dim3 grid((per_cg4 + 255) / 256, 32);
        riroi_pool_f16_v3<<<grid, 256, 0, stream>>>(wsf, rois, out, per_cg4);
    } else {
        const int total = n_rois * 32 * NBIN;
        riroi_rotated_fallback<<<(total + 255) / 256, 256, 0, stream>>>(feats, rois, out, total);
    }
}